// Round 1
// baseline (588.594 us; speedup 1.0000x reference)
//
#include <hip/hip_runtime.h>
#include <math.h>

// Problem constants (from reference setup_inputs)
#define NIMG_P 2      // N prediction images (softmaxed)
#define BB 8          // batch
#define HH 1024
#define WW 1024
#define HW (1024*1024)

#define TW 64         // tile width  (output pixels)
#define TH 32         // tile height (output pixels)
#define HALO_W (TW+6) // 70
#define HALO_H (TH+6) // 38
#define NCOPY 32      // accumulator copies to spread atomic contention
// per-image slot layout (18 doubles): [0]=sum(-logp)  [1]=sum(-logp*at)
//                                     [2+b]=I_b       [10+b]=U_b
#define NSLOT 18

__global__ __launch_bounds__(256)
void loss_main(const float* __restrict__ pred,
               const float* __restrict__ diss,
               const int*   __restrict__ target,
               double*      __restrict__ acc)
{
    __shared__ float tile[HALO_H][HALO_W]; // target with 3-halo, zero padded
    __shared__ float h5[HALO_H][TW];       // 5-wide horizontal sums (center col x+3)
    __shared__ float h7[HALO_H][TW];       // 7-wide horizontal sums
    __shared__ float red[4][12];

    const int bx = blockIdx.x;       // 0..15
    const int by = blockIdx.y;       // 0..31
    const int b  = blockIdx.z;       // 0..7
    const int x0 = bx * TW, y0 = by * TH;
    const int tx = threadIdx.x;              // 0..63
    const int tid = threadIdx.y * 64 + tx;   // 0..255

    // ---- stage 1: load target halo tile into LDS (zero pad at borders) ----
    const int* tgt_b = target + (size_t)b * HW;
    for (int idx = tid; idx < HALO_H * HALO_W; idx += 256) {
        int r = idx / HALO_W;
        int c = idx - r * HALO_W;
        int gy = y0 - 3 + r, gx = x0 - 3 + c;
        float v = 0.0f;
        if (gy >= 0 && gy < HH && gx >= 0 && gx < WW)
            v = (float)tgt_b[gy * WW + gx];
        tile[r][c] = v;
    }
    __syncthreads();

    // ---- stage 2: horizontal partial sums ----
    // h5[r][x] = sum of tile[r][x+1..x+5]  (center halo-col x+3, +-2)
    // h7[r][x] = sum of tile[r][x..x+6]    (center +-3)
    for (int idx = tid; idx < HALO_H * TW; idx += 256) {
        int r = idx >> 6;
        int x = idx & 63;
        float s5 = tile[r][x+1] + tile[r][x+2] + tile[r][x+3]
                 + tile[r][x+4] + tile[r][x+5];
        h5[r][x] = s5;
        h7[r][x] = s5 + tile[r][x] + tile[r][x+6];
    }
    __syncthreads();

    // ---- stage 3: per-pixel fused loss terms, 3 images at once ----
    const float* p00 = pred + ((size_t)(0*BB + b) * 2 + 0) * HW;
    const float* p01 = p00 + HW;
    const float* p10 = pred + ((size_t)(1*BB + b) * 2 + 0) * HW;
    const float* p11 = p10 + HW;
    const float* q0  = diss + ((size_t)b * 2 + 0) * HW;
    const float* q1  = q0 + HW;

    float sf0=0.f, se0=0.f, si0=0.f, su0=0.f;
    float sf1=0.f, se1=0.f, si1=0.f, su1=0.f;
    float sf2=0.f, se2=0.f, si2=0.f, su2=0.f;

    #pragma unroll
    for (int k = 0; k < TH/4; ++k) {
        const int r  = threadIdx.y + 4*k;   // 0..31 (output row in tile)
        const int gy = y0 + r;
        const int gx = x0 + tx;
        const float t = tile[r+3][tx+3];
        // circular 7x7 count: rows dy=-3..3 with widths 1,5,5,7,5,5,1
        const float cnt = tile[r][tx+3]
                        + h5[r+1][tx] + h5[r+2][tx]
                        + h7[r+3][tx]
                        + h5[r+4][tx] + h5[r+5][tx]
                        + tile[r+6][tx+3];
        const float at = fabsf(t - cnt * (1.0f/29.0f));
        const size_t off = (size_t)gy * WW + gx;

        // image 0 (softmax over 2 channels)
        {
            float a0 = p00[off], a1 = p01[off];
            float e   = __expf(a0 - a1);
            float p1v = __builtin_amdgcn_rcpf(1.0f + e); // softmax ch1
            float p0v = 1.0f - p1v;
            float pt  = (t != 0.0f) ? p1v : p0v;
            float lp  = __logf(pt + 1e-10f);
            sf0 -= lp; se0 -= lp * at; si0 += p1v * t; su0 += p1v + t;
        }
        // image 1
        {
            float a0 = p10[off], a1 = p11[off];
            float e   = __expf(a0 - a1);
            float p1v = __builtin_amdgcn_rcpf(1.0f + e);
            float p0v = 1.0f - p1v;
            float pt  = (t != 0.0f) ? p1v : p0v;
            float lp  = __logf(pt + 1e-10f);
            sf1 -= lp; se1 -= lp * at; si1 += p1v * t; su1 += p1v + t;
        }
        // Diss image (raw probabilities, no softmax)
        {
            float d0 = q0[off], d1 = q1[off];
            float pt = (t != 0.0f) ? d1 : d0;
            float lp = __logf(pt + 1e-10f);
            sf2 -= lp; se2 -= lp * at; si2 += d1 * t; su2 += d1 + t;
        }
    }

    // ---- stage 4: block reduction ----
    float vals[12] = {sf0,se0,si0,su0, sf1,se1,si1,su1, sf2,se2,si2,su2};
    #pragma unroll
    for (int j = 0; j < 12; ++j) {
        float v = vals[j];
        #pragma unroll
        for (int s = 32; s > 0; s >>= 1) v += __shfl_down(v, s, 64);
        vals[j] = v;
    }
    const int wave = tid >> 6;
    const int lane = tid & 63;
    if (lane == 0) {
        #pragma unroll
        for (int j = 0; j < 12; ++j) red[wave][j] = vals[j];
    }
    __syncthreads();
    if (tid < 12) {
        double s = (double)red[0][tid] + (double)red[1][tid]
                 + (double)red[2][tid] + (double)red[3][tid];
        const int img  = tid >> 2;   // 0..2
        const int what = tid & 3;    // 0 focal,1 edge,2 I,3 U
        int slot;
        if      (what == 0) slot = 0;
        else if (what == 1) slot = 1;
        else if (what == 2) slot = 2 + b;
        else                slot = 10 + b;
        const int copy = (blockIdx.y * 16 + blockIdx.x) & (NCOPY - 1);
        double* a = acc + ((size_t)copy * 3 + img) * NSLOT + slot;
        unsafeAtomicAdd(a, s);  // native global_atomic_add_f64
    }
}

__global__ void finalize_kernel(const double* __restrict__ acc,
                                const float*  __restrict__ diff,
                                const float*  __restrict__ sigma,
                                float*        __restrict__ out)
{
    if (threadIdx.x != 0 || blockIdx.x != 0) return;

    double A[3][NSLOT];
    for (int i = 0; i < 3; ++i)
        for (int s = 0; s < NSLOT; ++s) {
            double t = 0.0;
            for (int c = 0; c < NCOPY; ++c)
                t += acc[((size_t)c * 3 + i) * NSLOT + s];
            A[i][s] = t;
        }

    const double sig0 = (double)sigma[0] * (double)sigma[0];
    const double sig1 = (double)sigma[1] * (double)sigma[1];
    const double sig2 = (double)sigma[2] * (double)sigma[2];
    const double inv  = 1.0 / (double)((size_t)BB * HW); // mean over B*H*W

    double loss = 0.0;
    for (int i = 0; i < 3; ++i) {
        double focal = A[i][0] * inv;
        double edge  = A[i][1] * inv;
        double dsum  = 0.0;
        for (int b = 0; b < BB; ++b)
            dsum += 2.0 * A[i][2 + b] / (A[i][10 + b] + 1e-10);
        double dice = 1.0 - dsum / (double)BB;
        loss += focal / sig0 + dice / sig1 + edge / sig2;
    }
    loss += (double)diff[0];
    loss += 0.5 * (log(sig0) + log(sig1) + log(sig2));
    out[0] = (float)loss;
}

extern "C" void kernel_launch(void* const* d_in, const int* in_sizes, int n_in,
                              void* d_out, int out_size, void* d_ws, size_t ws_size,
                              hipStream_t stream)
{
    const float* pred   = (const float*)d_in[0]; // (2,8,2,1024,1024)
    const float* diss   = (const float*)d_in[1]; // (1,8,2,1024,1024)
    const int*   target = (const int*)  d_in[2]; // (8,1024,1024)
    const float* diff   = (const float*)d_in[3]; // scalar
    const float* sigma  = (const float*)d_in[4]; // (3,)
    double* acc = (double*)d_ws;

    // zero the accumulators (ws is poisoned 0xAA before every launch)
    hipMemsetAsync(d_ws, 0, (size_t)NCOPY * 3 * NSLOT * sizeof(double), stream);

    dim3 grid(WW / TW, HH / TH, BB);   // (16, 32, 8)
    dim3 block(64, 4);
    loss_main<<<grid, block, 0, stream>>>(pred, diss, target, acc);

    finalize_kernel<<<1, 64, 0, stream>>>(acc, diff, sigma, (float*)d_out);
}

// Round 2
// 268.218 us; speedup vs baseline: 2.1945x; 2.1945x over previous
//
#include <hip/hip_runtime.h>
#include <math.h>

// Problem constants
#define BB 8
#define HH 1024
#define WW 1024
#define HW (1024*1024)

#define TW 128        // tile width (output px)
#define TH 16         // tile height
#define HALO_H (TH+6) // 22
#define TSTRIDE 136   // tile row stride (floats); stored_col = halo_col + 1 so
                      // halo col (4k+3) -> stored (4k+4): 16B aligned for float4
#define NCOPY 32
#define NSLOT 18      // per image: [0]=focal sum, [1]=edge sum, [2+b]=I_b, [10+b]=U_b
// acc layout: acc[(img*NSLOT + slot)*NCOPY + copy]

__global__ __launch_bounds__(256)
void loss_main(const float* __restrict__ pred,
               const float* __restrict__ diss,
               const int*   __restrict__ target,
               double*      __restrict__ acc)
{
    __shared__ float tile[HALO_H][TSTRIDE]; // 11.9 KB target halo (stored +1 pad)
    __shared__ float h5[HALO_H][TW];        // 11.2 KB 5-wide row sums
    __shared__ float h7[HALO_H][TW];        // 11.2 KB 7-wide row sums
    __shared__ float red[4][12];

    const int bx = blockIdx.x;   // 0..7
    const int by = blockIdx.y;   // 0..63
    const int b  = blockIdx.z;   // 0..7
    const int x0 = bx * TW, y0 = by * TH;
    const int tid = threadIdx.x;       // 0..255
    const int txx = tid & 31;          // x-group (4 px each)
    const int ty  = tid >> 5;          // 0..7

    // ---- stage 1: target halo -> LDS via int4 chunks ----
    // chunk m of row r covers gx = x0-4+4m .. +3  -> stored cols 4m..4m+3
    const int* tgt_b = target + (size_t)b * HW;
    for (int ch = tid; ch < HALO_H * 34; ch += 256) {
        int r = ch / 34;
        int m = ch - r * 34;
        int gy  = y0 - 3 + r;
        int gxb = x0 - 4 + 4 * m;
        float4 v = make_float4(0.f, 0.f, 0.f, 0.f);
        if (gy >= 0 && gy < HH) {
            if (gxb >= 0 && gxb + 3 < WW) {
                const int4 iv = *(const int4*)(tgt_b + (size_t)gy * WW + gxb);
                v.x = (float)iv.x; v.y = (float)iv.y;
                v.z = (float)iv.z; v.w = (float)iv.w;
            } else {
                #pragma unroll
                for (int j = 0; j < 4; ++j) {
                    int gx = gxb + j;
                    ((float*)&v)[j] = (gx >= 0 && gx < WW)
                        ? (float)tgt_b[(size_t)gy * WW + gx] : 0.f;
                }
            }
        }
        *(float4*)&tile[r][4 * m] = v;
    }
    __syncthreads();

    // ---- stage 2: horizontal sums, 4 outputs/item, float4 LDS IO ----
    // h5[r][x] = stored cols x+2..x+6 ; h7[r][x] = stored cols x+1..x+7
    for (int g = tid; g < HALO_H * 32; g += 256) {
        int r  = g >> 5;
        int xg = (g & 31) << 2;
        float4 c0 = *(const float4*)&tile[r][xg];       // stored x..x+3
        float4 c1 = *(const float4*)&tile[r][xg + 4];   // x+4..x+7
        float4 c2 = *(const float4*)&tile[r][xg + 8];   // x+8..x+11
        float s1 = c0.y, s2 = c0.z, s3 = c0.w;
        float s4 = c1.x, s5 = c1.y, s6 = c1.z, s7 = c1.w;
        float s8 = c2.x, s9 = c2.y, s10 = c2.z;
        float4 v5, v7;
        v5.x = s2 + s3 + s4 + s5 + s6;
        v5.y = s3 + s4 + s5 + s6 + s7;
        v5.z = s4 + s5 + s6 + s7 + s8;
        v5.w = s5 + s6 + s7 + s8 + s9;
        v7.x = v5.x + s1 + s7;
        v7.y = v5.y + s2 + s8;
        v7.z = v5.z + s3 + s9;
        v7.w = v5.w + s4 + s10;
        *(float4*)&h5[r][xg] = v5;
        *(float4*)&h7[r][xg] = v7;
    }
    __syncthreads();

    // ---- stage 3: fused per-pixel terms, 4 px/thread, 3 images ----
    const float* p00 = pred + ((size_t)(0 * BB + b) * 2 + 0) * HW;
    const float* p01 = p00 + HW;
    const float* p10 = pred + ((size_t)(1 * BB + b) * 2 + 0) * HW;
    const float* p11 = p10 + HW;
    const float* q0  = diss + ((size_t)b * 2 + 0) * HW;
    const float* q1  = q0 + HW;

    float sf0=0.f, se0=0.f, si0=0.f, su0=0.f;
    float sf1=0.f, se1=0.f, si1=0.f, su1=0.f;
    float sf2=0.f, se2=0.f, si2=0.f, su2=0.f;

    const int x  = txx * 4;
    const int gx = x0 + x;
    #pragma unroll
    for (int k = 0; k < 2; ++k) {
        const int r  = ty + 8 * k;       // 0..15
        const int gy = y0 + r;
        const size_t off = (size_t)gy * WW + gx;

        float4 t4  = *(const float4*)&tile[r + 3][x + 4];
        float4 top = *(const float4*)&tile[r    ][x + 4];
        float4 bot = *(const float4*)&tile[r + 6][x + 4];
        float4 a1v = *(const float4*)&h5[r + 1][x];
        float4 a2v = *(const float4*)&h5[r + 2][x];
        float4 a3v = *(const float4*)&h7[r + 3][x];
        float4 a4v = *(const float4*)&h5[r + 4][x];
        float4 a5v = *(const float4*)&h5[r + 5][x];

        float4 v00 = *(const float4*)(p00 + off);
        float4 v01 = *(const float4*)(p01 + off);
        float4 v10 = *(const float4*)(p10 + off);
        float4 v11 = *(const float4*)(p11 + off);
        float4 w0  = *(const float4*)(q0  + off);
        float4 w1  = *(const float4*)(q1  + off);

        float4 cnt;
        cnt.x = top.x + a1v.x + a2v.x + a3v.x + a4v.x + a5v.x + bot.x;
        cnt.y = top.y + a1v.y + a2v.y + a3v.y + a4v.y + a5v.y + bot.y;
        cnt.z = top.z + a1v.z + a2v.z + a3v.z + a4v.z + a5v.z + bot.z;
        cnt.w = top.w + a1v.w + a2v.w + a3v.w + a4v.w + a5v.w + bot.w;

        #pragma unroll
        for (int j = 0; j < 4; ++j) {
            const float t  = ((const float*)&t4)[j];
            const float at = fabsf(t - ((const float*)&cnt)[j] * (1.0f / 29.0f));
            // image 0 (softmax of 2 channels)
            {
                float a0 = ((const float*)&v00)[j], a1 = ((const float*)&v01)[j];
                float p1v = __builtin_amdgcn_rcpf(1.0f + __expf(a0 - a1));
                float pt  = (t != 0.0f) ? p1v : 1.0f - p1v;
                float lp  = __logf(pt + 1e-10f);
                sf0 -= lp; se0 -= lp * at; si0 += p1v * t; su0 += p1v + t;
            }
            // image 1
            {
                float a0 = ((const float*)&v10)[j], a1 = ((const float*)&v11)[j];
                float p1v = __builtin_amdgcn_rcpf(1.0f + __expf(a0 - a1));
                float pt  = (t != 0.0f) ? p1v : 1.0f - p1v;
                float lp  = __logf(pt + 1e-10f);
                sf1 -= lp; se1 -= lp * at; si1 += p1v * t; su1 += p1v + t;
            }
            // Diss (raw probs)
            {
                float d0 = ((const float*)&w0)[j], d1 = ((const float*)&w1)[j];
                float pt = (t != 0.0f) ? d1 : d0;
                float lp = __logf(pt + 1e-10f);
                sf2 -= lp; se2 -= lp * at; si2 += d1 * t; su2 += d1 + t;
            }
        }
    }

    // ---- stage 4: block reduction -> 12 f64 atomics ----
    float vals[12] = {sf0,se0,si0,su0, sf1,se1,si1,su1, sf2,se2,si2,su2};
    #pragma unroll
    for (int j = 0; j < 12; ++j) {
        float v = vals[j];
        #pragma unroll
        for (int s = 32; s > 0; s >>= 1) v += __shfl_down(v, s, 64);
        vals[j] = v;
    }
    const int wave = tid >> 6;
    const int lane = tid & 63;
    if (lane == 0) {
        #pragma unroll
        for (int j = 0; j < 12; ++j) red[wave][j] = vals[j];
    }
    __syncthreads();
    if (tid < 12) {
        double s = (double)red[0][tid] + (double)red[1][tid]
                 + (double)red[2][tid] + (double)red[3][tid];
        const int img  = tid >> 2;
        const int what = tid & 3;
        int slot;
        if      (what == 0) slot = 0;
        else if (what == 1) slot = 1;
        else if (what == 2) slot = 2 + b;
        else                slot = 10 + b;
        const int copy = (by * 8 + bx) & (NCOPY - 1);
        unsafeAtomicAdd(acc + ((size_t)(img * NSLOT + slot) * NCOPY + copy), s);
    }
}

__global__ __launch_bounds__(256)
void finalize_kernel(const double* __restrict__ acc,
                     const float*  __restrict__ diff,
                     const float*  __restrict__ sigma,
                     float*        __restrict__ out)
{
    __shared__ double ssum[54];
    const int t = threadIdx.x;
    if (t < 216) {
        const int slot_lin = t >> 2;   // 0..53 = img*18+slot
        const int part     = t & 3;
        const double* p = acc + (size_t)slot_lin * NCOPY + part * 8;
        double s = 0.0;
        #pragma unroll
        for (int j = 0; j < 8; ++j) s += p[j];
        s += __shfl_down(s, 1, 64);
        s += __shfl_down(s, 2, 64);
        if (part == 0) ssum[slot_lin] = s;
    }
    __syncthreads();
    if (t == 0) {
        const double sig0 = (double)sigma[0] * (double)sigma[0];
        const double sig1 = (double)sigma[1] * (double)sigma[1];
        const double sig2 = (double)sigma[2] * (double)sigma[2];
        const double inv  = 1.0 / (double)((size_t)BB * HW);
        double loss = 0.0;
        for (int i = 0; i < 3; ++i) {
            const double* A = ssum + i * NSLOT;
            double focal = A[0] * inv;
            double edge  = A[1] * inv;
            double dsum  = 0.0;
            for (int b = 0; b < BB; ++b)
                dsum += 2.0 * A[2 + b] / (A[10 + b] + 1e-10);
            double dice = 1.0 - dsum / (double)BB;
            loss += focal / sig0 + dice / sig1 + edge / sig2;
        }
        loss += (double)diff[0];
        loss += 0.5 * (log(sig0) + log(sig1) + log(sig2));
        out[0] = (float)loss;
    }
}

extern "C" void kernel_launch(void* const* d_in, const int* in_sizes, int n_in,
                              void* d_out, int out_size, void* d_ws, size_t ws_size,
                              hipStream_t stream)
{
    const float* pred   = (const float*)d_in[0]; // (2,8,2,1024,1024)
    const float* diss   = (const float*)d_in[1]; // (1,8,2,1024,1024)
    const int*   target = (const int*)  d_in[2]; // (8,1024,1024)
    const float* diff   = (const float*)d_in[3];
    const float* sigma  = (const float*)d_in[4];
    double* acc = (double*)d_ws;

    hipMemsetAsync(d_ws, 0, (size_t)3 * NSLOT * NCOPY * sizeof(double), stream);

    dim3 grid(WW / TW, HH / TH, BB);   // (8, 64, 8)
    loss_main<<<grid, 256, 0, stream>>>(pred, diss, target, acc);
    finalize_kernel<<<1, 256, 0, stream>>>(acc, diff, sigma, (float*)d_out);
}